// Round 12
// baseline (520.555 us; speedup 1.0000x reference)
//
#include <hip/hip_runtime.h>
#include <hip/hip_bf16.h>
#include <math.h>
#include <stdint.h>

typedef __hip_bfloat16 bf16;
typedef __attribute__((ext_vector_type(8))) short short8;
typedef __attribute__((ext_vector_type(4))) short short4v;
typedef __attribute__((ext_vector_type(4))) float f32x4;

#define Tt 2048
#define Dd 1024
#define Hh 16

__device__ __forceinline__ float b2f(bf16 v){ return __bfloat162float(v); }
__device__ __forceinline__ bf16  f2b(float v){ return __float2bfloat16(v); }

// async global->LDS, 16B per lane. HW scatters lane l to ldsbase + l*16.
__device__ __forceinline__ void async16(const void* g, void* l){
  __builtin_amdgcn_global_load_lds(
      (__attribute__((address_space(1))) void*)(g),
      (__attribute__((address_space(3))) void*)(l),
      16, 0, 0);
}

__device__ __forceinline__ int seg_t(int lr, int t0, int Lm1){ return t0 + (lr & Lm1); }
__device__ __forceinline__ size_t seg_grow(int lr, int b0, int t0, int Llog2, int Lm1){
  return ((size_t)(b0 + (lr >> Llog2)) * Tt) + (size_t)seg_t(lr, t0, Lm1);
}

// XCD-chunked bijective swizzle for 128-tiles: XCD j (= flat%8) owns a
// contiguous bm-chunk, iterating bn fastest. Requires gridDim.y%8==0.
__device__ __forceinline__ void xcd_swz(int& bn, int& bm, int& z){
  int nbm = gridDim.y;
  if((nbm & 7) == 0){
    int flat = blockIdx.x + (blockIdx.y << 3) + blockIdx.z * (nbm << 3);
    int j = flat & 7, k = flat >> 3;
    int cs = nbm >> 3;
    bn = (k & 7) << 7;
    int kk = k >> 3;
    bm = (j * cs + (kk % cs)) << 7;
    z  = kk / cs;
  } else {
    bn = blockIdx.x << 7; bm = blockIdx.y << 7; z = blockIdx.z;
  }
}

// Generic variant: arbitrary gridDim.x / gridDim.z. XCD j owns contiguous
// bm-chunk of gridDim.y/8 tiles; bn iterates fastest, then bm, then z.
// Bijective when gridDim.y%8==0 (else identity fallback).
__device__ __forceinline__ void xcd_swz_g(int& bn, int& bm, int& z){
  int gx = gridDim.x, gy = gridDim.y;
  if((gy & 7) == 0){
    int flat = blockIdx.x + gx * (blockIdx.y + gy * blockIdx.z);
    int j = flat & 7, k = flat >> 3;
    int cs = gy >> 3;
    int bn_t = k % gx; int kk = k / gx;
    int bm_t = j * cs + (kk % cs);
    z  = kk / cs;
    bn = bn_t << 7; bm = bm_t << 7;
  } else {
    bn = blockIdx.x << 7; bm = blockIdx.y << 7; z = blockIdx.z;
  }
}

struct MixP { const bf16* maa[5]; bf16* dst[5]; };
struct Proj4 { const bf16* A[4]; const bf16* Bt[4]; bf16* C[4]; };
struct ConvP { const void* src[20]; bf16* dst[20]; };
struct T5P  { const bf16* src[5]; bf16* dst[5]; };

// ---------------------------------------------------------------- dtype detect
__global__ __launch_bounds__(256) void k_detect(const unsigned short* __restrict__ xs,
                                                int* __restrict__ flag){
  __shared__ int bad;
  if(threadIdx.x == 0) bad = 0;
  __syncthreads();
  int local = 0;
  for(int i = threadIdx.x; i < 8192; i += 256){
    unsigned e = (xs[i] >> 7) & 0xFF;
    if(e >= 0xC0) local++;
  }
  if(local) atomicAdd(&bad, local);
  __syncthreads();
  if(threadIdx.x == 0) flag[0] = (bad > 16) ? 1 : 0;   // 1 = inputs are float32
}

// ---------------------------------------------------------------- fused canonicalize (all 20 arrays, x4 vectorized)
__global__ __launch_bounds__(256) void k_conv_all(ConvP p, const int* __restrict__ flag){
  const int PRE[21] = {0,8388608,8389632,8390656,8391680,8392704,8393728,8394752,
                       8558592,8722432,8723456,8788992,8854528,8855552,9904128,
                       10952704,12001280,13049856,14098432,14099456,14100480};
  int v = (blockIdx.x * 256 + threadIdx.x) * 4;
  if(v >= 14100480) return;
  int a = 0;
  #pragma unroll
  for(int i = 1; i < 20; i++) if(v >= PRE[i]) a = i;
  int off = v - PRE[a];
  bf16* d = p.dst[a] + off;
  if(flag[0]){
    f32x4 xv = *(const f32x4*)((const float*)p.src[a] + off);
    short4v o;
    #pragma unroll
    for(int j = 0; j < 4; j++) ((bf16*)&o)[j] = f2b(xv[j]);
    *(short4v*)d = o;
  } else {
    *(short4v*)d = *(const short4v*)((const short*)p.src[a] + off);
  }
}

// ---------------------------------------------------------------- 1024x1024 bf16 transpose, 5 weights in one launch
__global__ __launch_bounds__(256) void k_transpose5(T5P p){
  __shared__ bf16 tile[32][33];
  const bf16* __restrict__ src = p.src[blockIdx.z];
  bf16* __restrict__ dst       = p.dst[blockIdx.z];
  int bx = blockIdx.x * 32, by = blockIdx.y * 32;
  int tx = threadIdx.x & 31, ty = threadIdx.x >> 5;   // 32 x 8
  for(int r = ty; r < 32; r += 8)
    tile[r][tx] = src[(size_t)(by + r) * 1024 + bx + tx];
  __syncthreads();
  for(int r = ty; r < 32; r += 8)
    dst[(size_t)(bx + r) * 1024 + by + tx] = tile[tx][r];
}

// ---------------------------------------------------------------- generic transpose+pad: dst[Npad][K] = src[K][N]^T
__global__ __launch_bounds__(256) void k_transposeP(const bf16* __restrict__ src,
                                                    bf16* __restrict__ dst,
                                                    int K, int N, int Npad){
  int idx = blockIdx.x * 256 + threadIdx.x;
  if(idx >= Npad * K) return;
  int n = idx / K, k = idx - n * K;
  dst[idx] = (n < N) ? src[(size_t)k * N + n] : f2b(0.f);
}

// ---------------------------------------------------------------- W2T transpose, 5 channels in one launch
__global__ __launch_bounds__(256) void k_transposeP5(const bf16* __restrict__ src,
                                                     bf16* __restrict__ dst){
  int z = blockIdx.z;
  int idx = blockIdx.x * 256 + threadIdx.x;   // < 32768
  int n = idx >> 5, k = idx & 31;
  dst[(size_t)z * 32768 + idx] = src[(size_t)z * 32768 + (size_t)k * 1024 + n];
}

// ---------------------------------------------------------------- k_prep: xmx = x + (shift(x)-x)*tmx
__global__ __launch_bounds__(256) void k_prep(const bf16* __restrict__ x,
                                              const bf16* __restrict__ tmx,
                                              bf16* __restrict__ xmx,
                                              int b0, int t0, int Llog2){
  const int Lm1 = (1 << Llog2) - 1;
  int idx = blockIdx.x * 256 + threadIdx.x;
  int lr = idx >> 10, d = idx & 1023;
  size_t grow = seg_grow(lr, b0, t0, Llog2, Lm1);
  int tl = seg_t(lr, t0, Lm1);
  float xc = b2f(x[grow * Dd + d]);
  float xp = tl ? b2f(x[(grow - 1) * Dd + d]) : 0.f;
  xmx[idx] = f2b(xc + (xp - xc) * b2f(tmx[d]));
}

// ---------------------------------------------------------------- MFMA GEMM (fixed 1024x1024), 3-buf pipeline + XCD swizzle
constexpr int GEPI_BF16 = 0, GEPI_SILU = 1, GEPI_OUT = 2;

template<int EPI>
__global__ __launch_bounds__(256) void gemm_mfma(
    const bf16* __restrict__ A,
    const bf16* __restrict__ Bt,
    void* __restrict__ Cv,
    const int* __restrict__ oflag,
    int rowoff){
  __shared__ __align__(16) short lds3[3][8192];   // [buf][A:0..4095 | B:4096..8191]
  int tid = threadIdx.x;
  int bn, bm, zz;
  xcd_swz(bn, bm, zz);
  int w = tid >> 6, lane = tid & 63;
  int wm = (w & 1) * 64, wn = (w >> 1) * 64;
  int m16 = lane & 15, quad = lane >> 4;

  f32x4 acc[4][4];
  #pragma unroll
  for(int mi = 0; mi < 4; mi++)
    #pragma unroll
    for(int ni = 0; ni < 4; ni++)
      acc[mi][ni] = (f32x4){0.f, 0.f, 0.f, 0.f};

  int srow = tid >> 2;                        // 0..63 (rep adds 64)
  int c4   = ((tid & 3) - (srow >> 1)) & 3;   // rotated logical chunk to fetch
  const bf16* Ag = A  + (size_t)(bm + srow) * 1024 + c4 * 8;
  const bf16* Bg = Bt + (size_t)(bn + srow) * 1024 + c4 * 8;

  auto STG = [&](int buf, int t){
    int kb = t << 5;
    #pragma unroll
    for(int rep = 0; rep < 2; rep++){
      async16(Ag + (size_t)rep * 64 * 1024 + kb, &lds3[buf][rep * 2048 + w * 512]);
      async16(Bg + (size_t)rep * 64 * 1024 + kb, &lds3[buf][4096 + rep * 2048 + w * 512]);
    }
  };
  STG(0, 0); STG(1, 1);
  asm volatile("s_waitcnt vmcnt(4)" ::: "memory");
  __builtin_amdgcn_s_barrier();
  __builtin_amdgcn_sched_barrier(0);

  #pragma unroll
  for(int t = 0; t < 32; t++){
    const int bufR = t % 3;
    const int bufS = (t + 2) % 3;
    if(t + 2 < 32) STG(bufS, t + 2);
    const short* As_b = &lds3[bufR][0];
    const short* Bs_b = &lds3[bufR][4096];
    short8 af[4], bfr[4];
    #pragma unroll
    for(int mi = 0; mi < 4; mi++){
      int ar = wm + mi * 16 + m16;
      af[mi] = *(const short8*)(As_b + ar * 32 + ((quad + (ar >> 1)) & 3) * 8);
    }
    #pragma unroll
    for(int ni = 0; ni < 4; ni++){
      int br = wn + ni * 16 + m16;
      bfr[ni] = *(const short8*)(Bs_b + br * 32 + ((quad + (br >> 1)) & 3) * 8);
    }
    __builtin_amdgcn_s_setprio(1);
    #pragma unroll
    for(int mi = 0; mi < 4; mi++)
      #pragma unroll
      for(int ni = 0; ni < 4; ni++)
        acc[mi][ni] = __builtin_amdgcn_mfma_f32_16x16x32_bf16(af[mi], bfr[ni], acc[mi][ni], 0, 0, 0);
    __builtin_amdgcn_s_setprio(0);
    __builtin_amdgcn_sched_barrier(0);
    if(t + 2 < 32){
      asm volatile("s_waitcnt vmcnt(4)" ::: "memory");
    } else if(t + 2 == 32){
      asm volatile("s_waitcnt vmcnt(0)" ::: "memory");
    }
    if(t < 31){
      __builtin_amdgcn_s_barrier();
      __builtin_amdgcn_sched_barrier(0);
    }
  }
  #pragma unroll
  for(int mi = 0; mi < 4; mi++){
    #pragma unroll
    for(int ni = 0; ni < 4; ni++){
      #pragma unroll
      for(int r = 0; r < 4; r++){
        int row = bm + wm + mi * 16 + quad * 4 + r;
        int col = bn + wn + ni * 16 + m16;
        float v = acc[mi][ni][r];
        if constexpr(EPI == GEPI_BF16){
          ((bf16*)Cv)[(size_t)row * 1024 + col] = f2b(v);
        } else if constexpr(EPI == GEPI_SILU){
          ((bf16*)Cv)[(size_t)row * 1024 + col] = f2b(v / (1.f + expf(-v)));
        } else { // GEPI_OUT
          size_t off = (size_t)(row + rowoff) * 1024 + col;
          if(oflag[0]) ((float*)Cv)[off] = v;
          else         ((bf16*)Cv)[off]  = f2b(v);
        }
      }
    }
  }
}

// ---------------------------------------------------------------- 256x128 proj4 GEMM, 8 waves, BK=32, 3-buf rotation
// grid (8, 32, 4), 512 threads. 2 blocks/CU (72 KB LDS) -> block-level TLP.
__global__ __launch_bounds__(512) void gemm256(Proj4 prm){
  __shared__ __align__(16) short lds3[3][12288];   // [buf][A:0..8191 | B:8192..12287]
  int tid = threadIdx.x;
  int flat = blockIdx.x + (blockIdx.y << 3) + (blockIdx.z << 8);
  int j = flat & 7, k = flat >> 3;
  int bn = (k & 7) << 7;
  int kk = k >> 3;
  int bm = ((j << 2) + (kk & 3)) << 8;
  int z  = kk >> 2;
  const bf16* __restrict__ A  = prm.A[z];
  const bf16* __restrict__ Bt = prm.Bt[z];
  bf16* __restrict__ C        = prm.C[z];
  int w = tid >> 6, lane = tid & 63;
  int wm = (w & 1) * 128, wn = (w >> 1) * 32;
  int m16 = lane & 15, quad = lane >> 4;

  f32x4 acc[8][2];
  #pragma unroll
  for(int mi = 0; mi < 8; mi++)
    #pragma unroll
    for(int ni = 0; ni < 2; ni++)
      acc[mi][ni] = (f32x4){0.f, 0.f, 0.f, 0.f};

  int srow = tid >> 2;                        // 0..127
  int c4   = ((tid & 3) - (srow >> 1)) & 3;   // rotated logical chunk to fetch
  const bf16* Ag = A  + (size_t)(bm + srow) * 1024 + c4 * 8;
  const bf16* Bg = Bt + (size_t)(bn + srow) * 1024 + c4 * 8;

  auto STG = [&](int buf, int t){
    int kb = t << 5;
    async16(Ag + kb,                          &lds3[buf][w * 512]);
    async16(Ag + (size_t)128 * 1024 + kb,     &lds3[buf][4096 + w * 512]);
    async16(Bg + kb,                          &lds3[buf][8192 + w * 512]);
  };
  STG(0, 0); STG(1, 1);
  asm volatile("s_waitcnt vmcnt(3)" ::: "memory");
  __builtin_amdgcn_s_barrier();
  __builtin_amdgcn_sched_barrier(0);

  #pragma unroll
  for(int t = 0; t < 32; t++){
    const int bufR = t % 3;
    const int bufS = (t + 2) % 3;
    if(t + 2 < 32) STG(bufS, t + 2);       // overlaps with this step's compute
    const short* As_b = &lds3[bufR][0];
    const short* Bs_b = &lds3[bufR][8192];
    short8 af[8], bfr[2];
    #pragma unroll
    for(int mi = 0; mi < 8; mi++){
      int ar = wm + mi * 16 + m16;
      af[mi] = *(const short8*)(As_b + ar * 32 + ((quad + (ar >> 1)) & 3) * 8);
    }
    #pragma unroll
    for(int ni = 0; ni < 2; ni++){
      int br = wn + ni * 16 + m16;
      bfr[ni] = *(const short8*)(Bs_b + br * 32 + ((quad + (br >> 1)) & 3) * 8);
    }
    __builtin_amdgcn_s_setprio(1);
    #pragma unroll
    for(int mi = 0; mi < 8; mi++)
      #pragma unroll
      for(int ni = 0; ni < 2; ni++)
        acc[mi][ni] = __builtin_amdgcn_mfma_f32_16x16x32_bf16(af[mi], bfr[ni], acc[mi][ni], 0, 0, 0);
    __builtin_amdgcn_s_setprio(0);
    __builtin_amdgcn_sched_barrier(0);
    if(t + 2 < 32){
      asm volatile("s_waitcnt vmcnt(3)" ::: "memory");   // tile t+1 landed
    } else if(t + 2 == 32){
      asm volatile("s_waitcnt vmcnt(0)" ::: "memory");   // tile 31 landed
    }
    if(t < 31){
      __builtin_amdgcn_s_barrier();          // single barrier per step
      __builtin_amdgcn_sched_barrier(0);
    }
  }
  bool silu = (z == 3);
  #pragma unroll
  for(int mi = 0; mi < 8; mi++){
    #pragma unroll
    for(int ni = 0; ni < 2; ni++){
      #pragma unroll
      for(int r = 0; r < 4; r++){
        int row = bm + wm + mi * 16 + quad * 4 + r;
        int col = bn + wn + ni * 16 + m16;
        float v = acc[mi][ni][r];
        if(silu) v = v / (1.f + expf(-v));
        C[(size_t)row * 1024 + col] = f2b(v);
      }
    }
  }
}

// ---------------------------------------------------------------- fused 5-channel mix (K=32 MFMA + mix epilogue), XCD-swizzled
__global__ __launch_bounds__(256) void gemm_mix(
    const bf16* __restrict__ xxx,   // [M][160] ld 256
    const bf16* __restrict__ w2T,   // [5][1024][32]
    const bf16* __restrict__ xg,
    MixP prm, int b0, int t0, int Llog2){
  const int Lm1 = (1 << Llog2) - 1;
  __shared__ __align__(16) short As[128 * 32];
  __shared__ __align__(16) short Bs[128 * 32];
  int tid = threadIdx.x;
  int bn, bm, c;
  xcd_swz_g(bn, bm, c);
  int w = tid >> 6, lane = tid & 63;
  int wm = (w & 1) * 64, wn = (w >> 1) * 64;
  int m16 = lane & 15, quad = lane >> 4;

  int srow = tid >> 2;
  int sk8  = (tid & 3) * 8;
  short* Al = As + w * 512;
  short* Bl = Bs + w * 512;
  #pragma unroll
  for(int rep = 0; rep < 2; rep++){
    async16(xxx + (size_t)(bm + srow + rep * 64) * 256 + c * 32 + sk8, Al + rep * 2048);
    async16(w2T + (size_t)c * 32768 + (size_t)(bn + srow + rep * 64) * 32 + sk8, Bl + rep * 2048);
  }
  __syncthreads();
  f32x4 acc[4][4];
  short8 af[4], bfr[4];
  #pragma unroll
  for(int mi = 0; mi < 4; mi++)
    af[mi] = *(const short8*)(As + (wm + mi * 16 + m16) * 32 + quad * 8);
  #pragma unroll
  for(int ni = 0; ni < 4; ni++)
    bfr[ni] = *(const short8*)(Bs + (wn + ni * 16 + m16) * 32 + quad * 8);
  #pragma unroll
  for(int mi = 0; mi < 4; mi++)
    #pragma unroll
    for(int ni = 0; ni < 4; ni++)
      acc[mi][ni] = __builtin_amdgcn_mfma_f32_16x16x32_bf16(
          af[mi], bfr[ni], (f32x4){0.f, 0.f, 0.f, 0.f}, 0, 0, 0);

  const bf16* maa = prm.maa[c];
  bf16* dst = prm.dst[c];
  #pragma unroll
  for(int mi = 0; mi < 4; mi++){
    #pragma unroll
    for(int ni = 0; ni < 4; ni++){
      #pragma unroll
      for(int r = 0; r < 4; r++){
        int row = bm + wm + mi * 16 + quad * 4 + r;
        int col = bn + wn + ni * 16 + m16;
        size_t grow = seg_grow(row, b0, t0, Llog2, Lm1);
        int tl = seg_t(row, t0, Lm1);
        float xc = b2f(xg[grow * Dd + col]);
        float xp = tl ? b2f(xg[(grow - 1) * Dd + col]) : 0.f;
        dst[(size_t)row * 1024 + col] =
            f2b(xc + (xp - xc) * (b2f(maa[col]) + acc[mi][ni][r]));
      }
    }
  }
}

// ---------------------------------------------------------------- generic MFMA GEMM (runtime N/K), XCD-swizzled
constexpr int G2_TANH = 0, G2_DECAY = 1;

template<int EPI>
__global__ __launch_bounds__(256) void gemm_mfma2(
    const bf16* __restrict__ A,
    const bf16* __restrict__ Bt,
    void* __restrict__ Cv, int ldc,
    int Ndim, int Kdim,
    const bf16* __restrict__ e_w){
  __shared__ __align__(16) short As[128 * 32];
  __shared__ __align__(16) short Bs[128 * 32];
  int tid = threadIdx.x;
  int bn, bm, zz;
  xcd_swz_g(bn, bm, zz);
  int w = tid >> 6, lane = tid & 63;
  int wm = (w & 1) * 64, wn = (w >> 1) * 64;
  int m16 = lane & 15, quad = lane >> 4;

  f32x4 acc[4][4];
  #pragma unroll
  for(int mi = 0; mi < 4; mi++)
    #pragma unroll
    for(int ni = 0; ni < 4; ni++)
      acc[mi][ni] = (f32x4){0.f, 0.f, 0.f, 0.f};

  int srow = tid >> 2;
  int sk8  = (tid & 3) * 8;
  const bf16* Ag = A  + (size_t)(bm + srow) * Kdim + sk8;
  const bf16* Bg = Bt + (size_t)(bn + srow) * Kdim + sk8;
  short* Al = As + w * 512;
  short* Bl = Bs + w * 512;

  for(int kb = 0; kb < Kdim; kb += 32){
    #pragma unroll
    for(int rep = 0; rep < 2; rep++){
      async16(Ag + (size_t)rep * 64 * Kdim + kb, Al + rep * 2048);
      async16(Bg + (size_t)rep * 64 * Kdim + kb, Bl + rep * 2048);
    }
    __syncthreads();
    short8 af[4], bfr[4];
    #pragma unroll
    for(int mi = 0; mi < 4; mi++)
      af[mi] = *(const short8*)(As + (wm + mi * 16 + m16) * 32 + quad * 8);
    #pragma unroll
    for(int ni = 0; ni < 4; ni++)
      bfr[ni] = *(const short8*)(Bs + (wn + ni * 16 + m16) * 32 + quad * 8);
    #pragma unroll
    for(int mi = 0; mi < 4; mi++)
      #pragma unroll
      for(int ni = 0; ni < 4; ni++)
        acc[mi][ni] = __builtin_amdgcn_mfma_f32_16x16x32_bf16(af[mi], bfr[ni], acc[mi][ni], 0, 0, 0);
    __syncthreads();
  }
  #pragma unroll
  for(int mi = 0; mi < 4; mi++){
    #pragma unroll
    for(int ni = 0; ni < 4; ni++){
      #pragma unroll
      for(int r = 0; r < 4; r++){
        int row = bm + wm + mi * 16 + quad * 4 + r;
        int col = bn + wn + ni * 16 + m16;
        if(col >= Ndim) continue;
        float v = acc[mi][ni][r];
        size_t off = (size_t)row * ldc + col;
        if constexpr(EPI == G2_TANH){
          ((bf16*)Cv)[off] = f2b(tanhf(v));
        } else { // G2_DECAY
          float td = b2f(e_w[col]) + v;
          ((float*)Cv)[off] = fmaxf(-expf(td), -5.2983173665480363f);
        }
      }
    }
  }
}

// ---------------------------------------------------------------- small VALU GEMM (segmented-out fallback only)
constexpr int EPI_OUTV = 5;
#define BM 64
#define BN 64
#define BK 16

template<int EPI>
__global__ __launch_bounds__(256) void gemm_ep(
    const bf16* __restrict__ A, int lda,
    const bf16* __restrict__ Bm, int ldb,
    void* __restrict__ Cv, int ldc,
    int Mdim, int Ndim, int Kdim,
    const bf16* __restrict__ xg, const bf16* __restrict__ e_w,
    int b0, int t0, int Llog2, const int* __restrict__ oflag){
  const int Lm1 = (1 << Llog2) - 1;
  __shared__ float As[BM][BK + 1];
  __shared__ float Bs[BK][BN + 4];
  int tid = threadIdx.x;
  int tx = tid & 15, ty = tid >> 4;
  int bm = blockIdx.y * BM, bn = blockIdx.x * BN;
  float acc[4][4] = {};
  for(int kb = 0; kb < Kdim; kb += BK){
    {
      int lr = tid >> 2;
      int lc = (tid & 3) * 4;
      int gr = bm + lr;
      #pragma unroll
      for(int q = 0; q < 4; q++){
        int gc = kb + lc + q;
        float av = 0.f;
        if(gr < Mdim && gc < Kdim)
          av = b2f(A[(size_t)gr * lda + gc]);
        As[lr][lc + q] = av;
      }
    }
    {
      int lr = tid >> 4;
      int lc = (tid & 15) * 4;
      #pragma unroll
      for(int q = 0; q < 4; q++){
        int gr = kb + lr; int gc = bn + lc + q;
        Bs[lr][lc + q] = (gr < Kdim && gc < Ndim) ? b2f(Bm[(size_t)gr * ldb + gc]) : 0.f;
      }
    }
    __syncthreads();
    #pragma unroll
    for(int kk = 0; kk < BK; kk++){
      float ar[4], br[4];
      #pragma unroll
      for(int q = 0; q < 4; q++) ar[q] = As[ty * 4 + q][kk];
      #pragma unroll
      for(int q = 0; q < 4; q++) br[q] = Bs[kk][tx * 4 + q];
      #pragma unroll
      for(int mi = 0; mi < 4; mi++)
        #pragma unroll
        for(int ni = 0; ni < 4; ni++)
          acc[mi][ni] += ar[mi] * br[ni];
    }
    __syncthreads();
  }
  #pragma unroll
  for(int mi = 0; mi < 4; mi++){
    int row = bm + ty * 4 + mi;
    if(row >= Mdim) continue;
    #pragma unroll
    for(int ni = 0; ni < 4; ni++){
      int col = bn + tx * 4 + ni;
      if(col >= Ndim) continue;
      float vacc = acc[mi][ni];
      size_t grow = seg_grow(row, b0, t0, Llog2, Lm1);
      size_t go = grow * Dd + col;
      if(oflag[0]) ((float*)Cv)[go] = vacc;
      else         ((bf16*)Cv)[go]  = f2b(vacc);
    }
  }
}

// ---------------------------------------------------------------- cumsum (in place wlog->wcum) + wse
__global__ __launch_bounds__(256) void k_cumsum(float* __restrict__ wd,
                                                float* __restrict__ wse,
                                                int nlog2){
  int blk = blockIdx.x;
  int dg = blk & 3; int rest = blk >> 2;
  int nmask = (1 << nlog2) - 1;
  int ln = rest & nmask; int bp = rest >> nlog2;
  int d = dg * 256 + threadIdx.x;
  size_t rowbase = (((size_t)bp << nlog2) + ln) * 128;
  size_t base = rowbase * Dd + d;
  float c = 0.f;
  for(int t = 0; t < 128; t++){
    size_t ix = base + (size_t)t * Dd;
    c += wd[ix];
    wd[ix] = c;
  }
  int h = d >> 6, k0 = d & 63;
  wse[((((size_t)bp * Hh + h) << nlog2) | ln) * 64 + k0] = __expf(fminf(c, 0.f));
}

// ---------------------------------------------------------------- chunk1 (MFMA)
__global__ __launch_bounds__(256) void k_chunk1(const bf16* __restrict__ kb,
                                                const bf16* __restrict__ vb,
                                                const float* __restrict__ wcum,
                                                float* __restrict__ wkv,
                                                int nlog2){
  __shared__ __align__(16) bf16 ktT[64 * 136];
  __shared__ __align__(16) bf16 vT2[64 * 136];
  int tid = threadIdx.x, blk = blockIdx.x;
  int nmask = (1 << nlog2) - 1;
  int ln = blk & nmask; int rest = blk >> nlog2;
  int h = rest & 15; int bp = rest >> 4;
  size_t rowbase = (((size_t)bp << nlog2) + ln) * 128;
  size_t gbase = rowbase * Dd + h * 64;
  for(int r = 0; r < 32; r++){
    int idx = r * 256 + tid;
    int t0 = idx >> 6, k0 = idx & 63;
    size_t gi = gbase + (size_t)t0 * Dd + k0;
    float c  = wcum[gi];
    float cL = wcum[gbase + (size_t)127 * Dd + k0];
    ktT[k0 * 136 + t0] = f2b(b2f(kb[gi]) * __expf(fminf(cL - c, 0.f)));
    vT2[k0 * 136 + t0] = vb[gi];
  }
  __syncthreads();
  int w = tid >> 6, lane = tid & 63;
  int m16 = lane & 15, quad = lane >> 4;
  f32x4 acc[4];
  #pragma unroll
  for(int nt = 0; nt < 4; nt++) acc[nt] = (f32x4){0.f, 0.f, 0.f, 0.f};
  #pragma unroll
  for(int ks = 0; ks < 4; ks++){
    short8 af = *(const short8*)(ktT + (w * 16 + m16) * 136 + ks * 32 + quad * 8);
    #pragma unroll
    for(int nt = 0; nt < 4; nt++){
      short8 bfr = *(const short8*)(vT2 + (nt * 16 + m16) * 136 + ks * 32 + quad * 8);
      acc[nt] = __builtin_amdgcn_mfma_f32_16x16x32_bf16(af, bfr, acc[nt], 0, 0, 0);
    }
  }
  size_t obase = (size_t)blk * 4096;
  #pragma unroll
  for(int nt = 0; nt < 4; nt++)
    #pragma unroll
    for(int r = 0; r < 4; r++)
      wkv[obase + (size_t)(w * 16 + quad * 4 + r) * 64 + nt * 16 + m16] = acc[nt][r];
}

// ---------------------------------------------------------------- state scan, in place, carry in st
__global__ __launch_bounds__(256) void k_scan(float* __restrict__ buf,
                                              const float* __restrict__ wse,
                                              float* __restrict__ st,
                                              int b0, int firstseg, int nlog2){
  int blk = blockIdx.x;
  int h = blk & 15, bp = blk >> 4;
  int tid = threadIdx.x;
  size_t stbase = ((size_t)(b0 + bp) * Hh + h) * 4096;
  int nloc = 1 << nlog2;
  float s[16];
  #pragma unroll
  for(int r = 0; r < 16; r++)
    s[r] = firstseg ? 0.f : st[stbase + r * 256 + tid];
  for(int ln = 0; ln < nloc; ln++){
    size_t idx = (((size_t)bp * Hh + h) << nlog2) | ln;
    size_t base = idx * 4096;
    const float* wsp = wse + idx * 64;
    #pragma unroll
    for(int r = 0; r < 16; r++){
      int e = r * 256 + tid;
      float tmp = buf[base + e];
      buf[base + e] = s[r];
      s[r] = s[r] * wsp[e >> 6] + tmp;
    }
  }
  #pragma unroll
  for(int r = 0; r < 16; r++)
    st[stbase + r * 256 + tid] = s[r];
}

// ---------------------------------------------------------------- chunk2: full-MFMA intra attention + fused groupnorm(64)+gate
__global__ __launch_bounds__(256) void k_chunk2(
    const bf16* __restrict__ rb, const bf16* __restrict__ kb,
    const bf16* __restrict__ vb, const float* __restrict__ wcum,
    const float* __restrict__ states, const bf16* __restrict__ u,
    const bf16* __restrict__ gb, const bf16* __restrict__ lnw,
    const bf16* __restrict__ lnb, bf16* __restrict__ gated,
    int nlog2){
  __shared__ __align__(16) bf16 vT[64 * 136];
  __shared__ __align__(16) bf16 sT[64 * 72];
  __shared__ __align__(16) bf16 ascr[4 * 16 * 136];
  int tid = threadIdx.x, blk = blockIdx.x;
  int nmask = (1 << nlog2) - 1;
  int ln = blk & nmask; int rest = blk >> nlog2;
  int h = rest & 15; int bp = rest >> 4;
  size_t rowbase = (((size_t)bp << nlog2) + ln) * 128;
  size_t gbase = rowbase * Dd + h * 64;
  for(int r = 0; r < 32; r++){
    int idx = r * 256 + tid;
    int t0 = idx >> 6, v0 = idx & 63;
    vT[v0 * 136 + t0] = vb[gbase + (size_t)t0 * Dd + v0];
  }
  for(int r = 0; r < 16; r++){
    int idx = r * 256 + tid;
    int k0 = idx >> 6, v0 = idx & 63;
    sT[v0 * 72 + k0] = f2b(states[(size_t)blk * 4096 + k0 * 64 + v0]);
  }
  __syncthreads();
  int w = tid >> 6, lane = tid & 63;
  int m16 = lane & 15, quad = lane >> 4;
  bf16* scr = ascr + w * (16 * 136);
  f32x4 oacc[2][4];
  #pragma unroll
  for(int a1 = 0; a1 < 2; a1++)
    #pragma unroll
    for(int a2 = 0; a2 < 4; a2++) oacc[a1][a2] = (f32x4){0.f, 0.f, 0.f, 0.f};

  for(int ii = 0; ii < 2; ii++){
    int I = ii ? (7 - w) : w;
    int B = I * 16;
    for(int z = lane; z < 544; z += 64) ((unsigned long long*)scr)[z] = 0ULL;
    int i0 = B + m16;
    size_t rowi = rowbase + i0;
    short8 rf[2], af[2], rw2[2];
    float crv[2][8];
    #pragma unroll
    for(int ks = 0; ks < 2; ks++){
      int koff = h * 64 + ks * 32 + quad * 8;
      rf[ks] = *(const short8*)(rb + rowi * Dd + koff);
      float cp[8];
      if(i0 > 0){
        f32x4 c0 = *(const f32x4*)(wcum + (rowi - 1) * Dd + koff);
        f32x4 c1 = *(const f32x4*)(wcum + (rowi - 1) * Dd + koff + 4);
        #pragma unroll
        for(int c = 0; c < 4; c++){ cp[c] = c0[c]; cp[4 + c] = c1[c]; }
      } else {
        #pragma unroll
        for(int c = 0; c < 8; c++) cp[c] = 0.f;
      }
      if(B > 0){
        f32x4 c0 = *(const f32x4*)(wcum + (rowbase + B - 1) * Dd + koff);
        f32x4 c1 = *(const f32x4*)(wcum + (rowbase + B - 1) * Dd + koff + 4);
        #pragma unroll
        for(int c = 0; c < 4; c++){ crv[ks][c] = c0[c]; crv[ks][4 + c] = c1[c]; }
      } else {
        #pragma unroll
        for(int c = 0; c < 8; c++) crv[ks][c] = 0.f;
      }
      short8 av, wv;
      #pragma unroll
      for(int c = 0; c < 8; c++){
        float rv = b2f(((const bf16*)&rf[ks])[c]);
        ((bf16*)&av)[c] = f2b(rv * __expf(fminf(cp[c] - crv[ks][c], 0.f)));
        ((bf16*)&wv)[c] = f2b(rv * __expf(fminf(cp[c], 0.f)));
      }
      af[ks] = av; rw2[ks] = wv;
    }
    for(int J = 0; J < I; J++){
      f32x4 aacc = (f32x4){0.f, 0.f, 0.f, 0.f};
      #pragma unroll
      for(int ks = 0; ks < 2; ks++){
        int koff = h * 64 + ks * 32 + quad * 8;
        size_t rowj = rowbase + J * 16 + m16;
        short8 k8 = *(const short8*)(kb + rowj * Dd + koff);
        f32x4 c0 = *(const f32x4*)(wcum + rowj * Dd + koff);
        f32x4 c1 = *(const f32x4*)(wcum + rowj * Dd + koff + 4);
        short8 bfrag;
        #pragma unroll
        for(int c = 0; c < 8; c++){
          float kv = b2f(((const bf16*)&k8)[c]);
          float cj = (c < 4) ? c0[c] : c1[c - 4];
          ((bf16*)&bfrag)[c] = f2b(kv * __expf(fminf(crv[ks][c] - cj, 0.f)));
        }
        aacc = __builtin_amdgcn_mfma_f32_16x16x32_bf16(af[ks], bfrag, aacc, 0, 0, 0);
      }
      #pragma unroll
      for(int r = 0; r < 4; r++)
        scr[(quad * 4 + r) * 136 + J * 16 + m16] = f2b(aacc[r]);
    }
    {
      f32x4 aacc = (f32x4){0.f, 0.f, 0.f, 0.f};
      f32x4 dacc = (f32x4){0.f, 0.f, 0.f, 0.f};
      #pragma unroll
      for(int ks = 0; ks < 2; ks++){
        int koff = h * 64 + ks * 32 + quad * 8;
        size_t rowj = rowbase + B + m16;
        short8 k8 = *(const short8*)(kb + rowj * Dd + koff);
        f32x4 c0 = *(const f32x4*)(wcum + rowj * Dd + koff);
        f32x4 c1 = *(const f32x4*)(wcum + rowj * Dd + koff + 4);
        short8 u8 = *(const short8*)(u + h * 64 + ks * 32 + quad * 8);
        short8 bf1, bf2;
        #pragma unroll
        for(int c = 0; c < 8; c++){
          float kv = b2f(((const bf16*)&k8)[c]);
          float cj = (c < 4) ? c0[c] : c1[c - 4];
          ((bf16*)&bf1)[c] = f2b(kv * __expf(crv[ks][c] - cj));
          ((bf16*)&bf2)[c] = f2b(kv * b2f(((const bf16*)&u8)[c]));
        }
        aacc = __builtin_amdgcn_mfma_f32_16x16x32_bf16(af[ks], bf1, aacc, 0, 0, 0);
        dacc = __builtin_amdgcn_mfma_f32_16x16x32_bf16(rf[ks], bf2, dacc, 0, 0, 0);
      }
      #pragma unroll
      for(int r = 0; r < 4; r++){
        int row = quad * 4 + r, col = m16;
        if(col < row)       scr[row * 136 + B + col] = f2b(aacc[r]);
        else if(col == row) scr[row * 136 + B + col] = f2b(dacc[r]);
      }
    }
    asm volatile("s_waitcnt lgkmcnt(0)" ::: "memory");
    int nks = (I + 2) >> 1;
    for(int ks2 = 0; ks2 < nks; ks2++){
      short8 afr = *(const short8*)(scr + m16 * 136 + ks2 * 32 + quad * 8);
      #pragma unroll
      for(int nt = 0; nt < 4; nt++){
        short8 bfr = *(const short8*)(vT + (nt * 16 + m16) * 136 + ks2 * 32 + quad * 8);
        oacc[ii][nt] = __builtin_amdgcn_mfma_f32_16x16x32_bf16(afr, bfr, oacc[ii][nt], 0, 0, 0);
      }
    }
    #pragma unroll
    for(int ks = 0; ks < 2; ks++){
      #pragma unroll
      for(int nt = 0; nt < 4; nt++){
        short8 sfr = *(const short8*)(sT + (nt * 16 + m16) * 72 + ks * 32 + quad * 8);
        oacc[ii][nt] = __builtin_amdgcn_mfma_f32_16x16x32_bf16(rw2[ks], sfr, oacc[ii][nt], 0, 0, 0);
      }
    }
  }
  __syncthreads();
  // fused groupnorm(64) + gate: each wave holds rows B..B+15 x all 64 cols
  // of head h. Row (quad*4+r)'s 64 cols live in the 16 m16-lanes x 4 nt
  // fragments -> per-lane partial sums + shfl_xor over lane bits 0..3.
  #pragma unroll
  for(int ii = 0; ii < 2; ii++){
    int I = ii ? (7 - w) : w;
    int B = I * 16;
    #pragma unroll
    for(int r = 0; r < 4; r++){
      float s1 = 0.f, s2 = 0.f;
      #pragma unroll
      for(int nt = 0; nt < 4; nt++){
        float v = oacc[ii][nt][r];
        s1 += v; s2 += v * v;
      }
      #pragma unroll
      for(int off = 8; off > 0; off >>= 1){
        s1 += __shfl_xor(s1, off);
        s2 += __shfl_xor(s2, off);
      }
      float mu  = s1 * 0.015625f;
      float var = s2 * 0.015625f - mu * mu;
      float inv = rsqrtf(var + 6.4e-4f);
      int i0 = B + quad * 4 + r;
      size_t rowoff = gbase + (size_t)i0 * Dd;
      #pragma unroll
      for(int nt = 0; nt < 4; nt++){
        int v0 = nt * 16 + m16;
        float og = (oacc[ii][nt][r] - mu) * inv * b2f(lnw[h * 64 + v0]) + b2f(lnb[h * 64 + v0]);
        gated[rowoff + v0] = f2b(og * b2f(gb[rowoff + v0]));
      }
    }
  }
}

// ---------------------------------------------------------------- host
extern "C" void kernel_launch(void* const* d_in, const int* in_sizes, int n_in,
                              void* d_out, int out_size, void* d_ws, size_t ws_size,
                              hipStream_t stream){
  char* W = (char*)d_ws;
  size_t cur = 0;
  auto carve = [&](size_t bytes) -> char* {
    char* p = W + cur;
    cur = (cur + bytes + 255) & ~(size_t)255;
    return p;
  };

  int* flag = (int*)carve(4096);
  static const int NEL[20] = {8388608, 1024, 1024, 1024, 1024, 1024, 1024,
                              163840, 163840, 1024, 65536, 65536, 1024,
                              1048576, 1048576, 1048576, 1048576, 1048576,
                              1024, 1024};
  bf16* canon[20];
  for(int i = 0; i < 20; i++) canon[i] = (bf16*)carve((size_t)NEL[i] * 2);

  k_detect<<<dim3(1), 256, 0, stream>>>((const unsigned short*)d_in[0], flag);
  ConvP cp;
  for(int i = 0; i < 20; i++){ cp.src[i] = d_in[i]; cp.dst[i] = canon[i]; }
  k_conv_all<<<dim3(13770), 256, 0, stream>>>(cp, flag);

  const bf16* xp   = canon[0];
  const bf16* tmx  = canon[1];
  const bf16* tdec = canon[9];
  const bf16* up   = canon[12];
  const bf16* lnwp = canon[18];
  const bf16* lnbp = canon[19];

  bf16* WrT  = (bf16*)carve(2097152);
  bf16* WkT  = (bf16*)carve(2097152);
  bf16* WvT  = (bf16*)carve(2097152);
  bf16* WgT  = (bf16*)carve(2097152);
  bf16* WoT  = (bf16*)carve(2097152);
  bf16* W1T  = (bf16*)carve(256 * 1024 * 2);    // [256][1024], rows >=160 zero
  bf16* DW1T = (bf16*)carve(128 * 1024 * 2);    // [128][1024], rows >=64 zero
  bf16* DW2T = (bf16*)carve(1024 * 64 * 2);     // [1024][64]
  bf16* W2T  = (bf16*)carve(5 * 1024 * 32 * 2); // [5][1024][32]
  T5P tp;
  tp.src[0] = canon[13]; tp.dst[0] = WrT;
  tp.src[1] = canon[14]; tp.dst[1] = WkT;
  tp.src[2] = canon[15]; tp.dst[2] = WvT;
  tp.src[3] = canon[16]; tp.dst[3] = WgT;
  tp.src[4] = canon[17]; tp.dst[4] = WoT;
  k_transpose5<<<dim3(32, 32, 5), 256, 0, stream>>>(tp);
  k_transposeP<<<dim3(1024), 256, 0, stream>>>(canon[7],  W1T,  1024, 160, 256);
  k_transposeP<<<dim3(512),  256, 0, stream>>>(canon[10], DW1T, 1024, 64, 128);
  k_transposeP<<<dim3(256),  256, 0, stream>>>(canon[11], DW2T, 64, 1024, 1024);
  k_transposeP5<<<dim3(128, 1, 5), 256, 0, stream>>>(canon[8], W2T);

  float* st = (float*)carve(1u << 20);
  size_t FIXED = cur;

  // per-row bytes: xxx 512 + ww1 128 + wse 32 + xmx 2048 + mix 2048 + k/v/r/g 4*2048
  //              + wdec 4096 + wkvst 2048 = 19104
  const size_t UNIT = 19104, PAD = 65536;
  int nb, L;
  if(ws_size >= FIXED + (size_t)8192 * UNIT + PAD){ nb = 4; L = 2048; }
  else {
    nb = 1; L = 2048;
    while(L > 128 && ws_size < FIXED + (size_t)L * UNIT + PAD) L >>= 1;
  }
  const int Llog2 = __builtin_ctz((unsigned)L);
  const int nlog2 = Llog2 - 7;
  const int M     = nb * L;
  const size_t Mr = (size_t)M;

  bf16*  xxx    = (bf16*) carve(Mr * 512);     // [M][160] ld 256
  bf16*  ww1    = (bf16*) carve(Mr * 128);
  float* wse    = (float*)carve(Mr * 32);
  bf16*  xmx    = (bf16*) carve(Mr * 2048);
  bf16*  mixbuf = (bf16*) carve(Mr * 2048);
  bf16*  kbuf   = (bf16*) carve(Mr * 2048);
  bf16*  vbuf   = (bf16*) carve(Mr * 2048);
  bf16*  rbuf   = (bf16*) carve(Mr * 2048);
  bf16*  gbuf   = (bf16*) carve(Mr * 2048);
  float* wdec   = (float*)carve(Mr * 4096);
  float* wkvst  = (float*)carve(Mr * 2048);
  bf16*  gated  = mixbuf; // mixbuf dead after decay-tanh GEMM

  // channel overlay for the 5 fused-mix outputs (all dead-by-consumer ordering):
  //   mix5[0]=mixbuf (w, consumed by decay tanh), mix5[1]=wdec[0:16M] (k),
  //   mix5[2]=wdec[16M:32M] (v), mix5[3]=wkvst (r), mix5[4]=xmx (g, xmx dead post-LoRA)
  MixP mp;
  mp.maa[0] = canon[2]; mp.maa[1] = canon[3]; mp.maa[2] = canon[4];
  mp.maa[3] = canon[5]; mp.maa[4] = canon[6];
  mp.dst[0] = mixbuf;
  mp.dst[1] = (bf16*)wdec;
  mp.dst[2] = (bf16*)wdec + Mr * 1024;
  mp.dst[3] = (bf16*)wkvst;
  mp.dst[4] = xmx;

  Proj4 pp;
  pp.A[0] = mp.dst[1]; pp.Bt[0] = WkT; pp.C[0] = kbuf;
  pp.A[1] = mp.dst[2]; pp.Bt[1] = WvT; pp.C[1] = vbuf;
  pp.A[2] = mp.dst[3]; pp.Bt[2] = WrT; pp.C[2] = rbuf;
  pp.A[3] = mp.dst[4]; pp.Bt[3] = WgT; pp.C[3] = gbuf;

  for(int b0 = 0; b0 < 4; b0 += nb){
    for(int t0 = 0; t0 < Tt; t0 += L){
      // 1. xmx, then xxx = tanh(xmx @ w1)
      k_prep<<<dim3(M * 4), 256, 0, stream>>>(xp, tmx, xmx, b0, t0, Llog2);
      gemm_mfma2<G2_TANH><<<dim3(2, M/128), 256, 0, stream>>>(
          xmx, W1T, xxx, 256, 160, 1024, nullptr);
      // 2. fused 5-channel mix (xmx dead; overwritten as mix5[4])
      gemm_mix<<<dim3(8, M/128, 5), 256, 0, stream>>>(
          xxx, W2T, xp, mp, b0, t0, Llog2);
      // 3. four projections in one launch (256x128 tile, 3-buf pipeline, 2 blk/CU)
      if(M == 8192){
        gemm256<<<dim3(8, 32, 4), 512, 0, stream>>>(pp);
      } else {
        for(int z = 0; z < 4; z++){
          if(z == 3)
            gemm_mfma<GEPI_SILU><<<dim3(8, M/128), 256, 0, stream>>>(pp.A[z], pp.Bt[z], pp.C[z], flag, 0);
          else
            gemm_mfma<GEPI_BF16><<<dim3(8, M/128), 256, 0, stream>>>(pp.A[z], pp.Bt[z], pp.C[z], flag, 0);
        }
      }
      // 4. decay chain (consumes mix5[0]; writes wdec over mix5[1,2] — dead)
      gemm_mfma2<G2_TANH><<<dim3(1, M/128), 256, 0, stream>>>(
          mixbuf, DW1T, ww1, 64, 64, 1024, nullptr);
      gemm_mfma2<G2_DECAY><<<dim3(8, M/128), 256, 0, stream>>>(
          ww1, DW2T, wdec, 1024, 1024, 64, tdec);
      // 5. chunked WKV (chunk2 now fuses groupnorm+gate -> gated directly)
      int nloc = 1 << nlog2;
      k_cumsum<<<dim3(nb * nloc * 4), 256, 0, stream>>>(wdec, wse, nlog2);
      k_chunk1<<<dim3(nb * 16 * nloc), 256, 0, stream>>>(kbuf, vbuf, wdec, wkvst, nlog2);
      k_scan<<<dim3(nb * 16), 256, 0, stream>>>(wkvst, wse, st, b0, (t0 == 0) ? 1 : 0, nlog2);
      k_chunk2<<<dim3(nb * 16 * nloc), 256, 0, stream>>>(
          rbuf, kbuf, vbuf, wdec, wkvst, up, gbuf, lnwp, lnbp, gated, nlog2);
      // 6. output projection (3-buf pipelined 128^2, 512 blocks)
      if(L == Tt){
        gemm_mfma<GEPI_OUT><<<dim3(8, M/128), 256, 0, stream>>>(gated, WoT, d_out, flag, b0 * Tt);
      } else {
        gemm_ep<EPI_OUTV><<<dim3(16, M/64), 256, 0, stream>>>(
            gated, 1024, canon[17], 1024, d_out, 1024, M, 1024, 1024,
            nullptr, nullptr, b0, t0, Llog2, flag);
      }
    }
  }
}

// Round 13
// 517.954 us; speedup vs baseline: 1.0050x; 1.0050x over previous
//
#include <hip/hip_runtime.h>
#include <hip/hip_bf16.h>
#include <math.h>
#include <stdint.h>

typedef __hip_bfloat16 bf16;
typedef __attribute__((ext_vector_type(8))) short short8;
typedef __attribute__((ext_vector_type(4))) short short4v;
typedef __attribute__((ext_vector_type(4))) float f32x4;

#define Tt 2048
#define Dd 1024
#define Hh 16

__device__ __forceinline__ float b2f(bf16 v){ return __bfloat162float(v); }
__device__ __forceinline__ bf16  f2b(float v){ return __float2bfloat16(v); }

// async global->LDS, 16B per lane. HW scatters lane l to ldsbase + l*16.
__device__ __forceinline__ void async16(const void* g, void* l){
  __builtin_amdgcn_global_load_lds(
      (__attribute__((address_space(1))) void*)(g),
      (__attribute__((address_space(3))) void*)(l),
      16, 0, 0);
}

__device__ __forceinline__ int seg_t(int lr, int t0, int Lm1){ return t0 + (lr & Lm1); }
__device__ __forceinline__ size_t seg_grow(int lr, int b0, int t0, int Llog2, int Lm1){
  return ((size_t)(b0 + (lr >> Llog2)) * Tt) + (size_t)seg_t(lr, t0, Lm1);
}

// XCD-chunked bijective swizzle for 128-tiles: XCD j (= flat%8) owns a
// contiguous bm-chunk, iterating bn fastest. Requires gridDim.y%8==0.
__device__ __forceinline__ void xcd_swz(int& bn, int& bm, int& z){
  int nbm = gridDim.y;
  if((nbm & 7) == 0){
    int flat = blockIdx.x + (blockIdx.y << 3) + blockIdx.z * (nbm << 3);
    int j = flat & 7, k = flat >> 3;
    int cs = nbm >> 3;
    bn = (k & 7) << 7;
    int kk = k >> 3;
    bm = (j * cs + (kk % cs)) << 7;
    z  = kk / cs;
  } else {
    bn = blockIdx.x << 7; bm = blockIdx.y << 7; z = blockIdx.z;
  }
}

// Generic variant: arbitrary gridDim.x / gridDim.z. XCD j owns contiguous
// bm-chunk of gridDim.y/8 tiles; bn iterates fastest, then bm, then z.
// Bijective when gridDim.y%8==0 (else identity fallback).
__device__ __forceinline__ void xcd_swz_g(int& bn, int& bm, int& z){
  int gx = gridDim.x, gy = gridDim.y;
  if((gy & 7) == 0){
    int flat = blockIdx.x + gx * (blockIdx.y + gy * blockIdx.z);
    int j = flat & 7, k = flat >> 3;
    int cs = gy >> 3;
    int bn_t = k % gx; int kk = k / gx;
    int bm_t = j * cs + (kk % cs);
    z  = kk / cs;
    bn = bn_t << 7; bm = bm_t << 7;
  } else {
    bn = blockIdx.x << 7; bm = blockIdx.y << 7; z = blockIdx.z;
  }
}

struct MixP { const bf16* maa[5]; bf16* dst[5]; };
struct Proj4 { const bf16* A[4]; const bf16* Bt[4]; bf16* C[4]; };
struct ConvP { const void* src[20]; bf16* dst[20]; };
struct T5P  { const bf16* src[5]; bf16* dst[5]; };

// ---------------------------------------------------------------- dtype detect
__global__ __launch_bounds__(256) void k_detect(const unsigned short* __restrict__ xs,
                                                int* __restrict__ flag){
  __shared__ int bad;
  if(threadIdx.x == 0) bad = 0;
  __syncthreads();
  int local = 0;
  for(int i = threadIdx.x; i < 8192; i += 256){
    unsigned e = (xs[i] >> 7) & 0xFF;
    if(e >= 0xC0) local++;
  }
  if(local) atomicAdd(&bad, local);
  __syncthreads();
  if(threadIdx.x == 0) flag[0] = (bad > 16) ? 1 : 0;   // 1 = inputs are float32
}

// ---------------------------------------------------------------- fused canonicalize (all 20 arrays, x4 vectorized)
__global__ __launch_bounds__(256) void k_conv_all(ConvP p, const int* __restrict__ flag){
  const int PRE[21] = {0,8388608,8389632,8390656,8391680,8392704,8393728,8394752,
                       8558592,8722432,8723456,8788992,8854528,8855552,9904128,
                       10952704,12001280,13049856,14098432,14099456,14100480};
  int v = (blockIdx.x * 256 + threadIdx.x) * 4;
  if(v >= 14100480) return;
  int a = 0;
  #pragma unroll
  for(int i = 1; i < 20; i++) if(v >= PRE[i]) a = i;
  int off = v - PRE[a];
  bf16* d = p.dst[a] + off;
  if(flag[0]){
    f32x4 xv = *(const f32x4*)((const float*)p.src[a] + off);
    short4v o;
    #pragma unroll
    for(int j = 0; j < 4; j++) ((bf16*)&o)[j] = f2b(xv[j]);
    *(short4v*)d = o;
  } else {
    *(short4v*)d = *(const short4v*)((const short*)p.src[a] + off);
  }
}

// ---------------------------------------------------------------- 1024x1024 bf16 transpose, 5 weights in one launch
__global__ __launch_bounds__(256) void k_transpose5(T5P p){
  __shared__ bf16 tile[32][33];
  const bf16* __restrict__ src = p.src[blockIdx.z];
  bf16* __restrict__ dst       = p.dst[blockIdx.z];
  int bx = blockIdx.x * 32, by = blockIdx.y * 32;
  int tx = threadIdx.x & 31, ty = threadIdx.x >> 5;   // 32 x 8
  for(int r = ty; r < 32; r += 8)
    tile[r][tx] = src[(size_t)(by + r) * 1024 + bx + tx];
  __syncthreads();
  for(int r = ty; r < 32; r += 8)
    dst[(size_t)(bx + r) * 1024 + by + tx] = tile[tx][r];
}

// ---------------------------------------------------------------- generic transpose+pad: dst[Npad][K] = src[K][N]^T
__global__ __launch_bounds__(256) void k_transposeP(const bf16* __restrict__ src,
                                                    bf16* __restrict__ dst,
                                                    int K, int N, int Npad){
  int idx = blockIdx.x * 256 + threadIdx.x;
  if(idx >= Npad * K) return;
  int n = idx / K, k = idx - n * K;
  dst[idx] = (n < N) ? src[(size_t)k * N + n] : f2b(0.f);
}

// ---------------------------------------------------------------- W2T transpose, 5 channels in one launch
__global__ __launch_bounds__(256) void k_transposeP5(const bf16* __restrict__ src,
                                                     bf16* __restrict__ dst){
  int z = blockIdx.z;
  int idx = blockIdx.x * 256 + threadIdx.x;   // < 32768
  int n = idx >> 5, k = idx & 31;
  dst[(size_t)z * 32768 + idx] = src[(size_t)z * 32768 + (size_t)k * 1024 + n];
}

// ---------------------------------------------------------------- k_prep: xmx = x + (shift(x)-x)*tmx
__global__ __launch_bounds__(256) void k_prep(const bf16* __restrict__ x,
                                              const bf16* __restrict__ tmx,
                                              bf16* __restrict__ xmx,
                                              int b0, int t0, int Llog2){
  const int Lm1 = (1 << Llog2) - 1;
  int idx = blockIdx.x * 256 + threadIdx.x;
  int lr = idx >> 10, d = idx & 1023;
  size_t grow = seg_grow(lr, b0, t0, Llog2, Lm1);
  int tl = seg_t(lr, t0, Lm1);
  float xc = b2f(x[grow * Dd + d]);
  float xp = tl ? b2f(x[(grow - 1) * Dd + d]) : 0.f;
  xmx[idx] = f2b(xc + (xp - xc) * b2f(tmx[d]));
}

// ---------------------------------------------------------------- MFMA GEMM (fixed 1024x1024), 3-buf pipeline + XCD swizzle
constexpr int GEPI_BF16 = 0, GEPI_SILU = 1, GEPI_OUT = 2;

template<int EPI>
__global__ __launch_bounds__(256) void gemm_mfma(
    const bf16* __restrict__ A,
    const bf16* __restrict__ Bt,
    void* __restrict__ Cv,
    const int* __restrict__ oflag,
    int rowoff){
  __shared__ __align__(16) short lds3[3][8192];   // [buf][A:0..4095 | B:4096..8191]
  int tid = threadIdx.x;
  int bn, bm, zz;
  xcd_swz(bn, bm, zz);
  int w = tid >> 6, lane = tid & 63;
  int wm = (w & 1) * 64, wn = (w >> 1) * 64;
  int m16 = lane & 15, quad = lane >> 4;

  f32x4 acc[4][4];
  #pragma unroll
  for(int mi = 0; mi < 4; mi++)
    #pragma unroll
    for(int ni = 0; ni < 4; ni++)
      acc[mi][ni] = (f32x4){0.f, 0.f, 0.f, 0.f};

  int srow = tid >> 2;                        // 0..63 (rep adds 64)
  int c4   = ((tid & 3) - (srow >> 1)) & 3;   // rotated logical chunk to fetch
  const bf16* Ag = A  + (size_t)(bm + srow) * 1024 + c4 * 8;
  const bf16* Bg = Bt + (size_t)(bn + srow) * 1024 + c4 * 8;

  auto STG = [&](int buf, int t){
    int kb = t << 5;
    #pragma unroll
    for(int rep = 0; rep < 2; rep++){
      async16(Ag + (size_t)rep * 64 * 1024 + kb, &lds3[buf][rep * 2048 + w * 512]);
      async16(Bg + (size_t)rep * 64 * 1024 + kb, &lds3[buf][4096 + rep * 2048 + w * 512]);
    }
  };
  STG(0, 0); STG(1, 1);
  asm volatile("s_waitcnt vmcnt(4)" ::: "memory");
  __builtin_amdgcn_s_barrier();
  __builtin_amdgcn_sched_barrier(0);

  #pragma unroll
  for(int t = 0; t < 32; t++){
    const int bufR = t % 3;
    const int bufS = (t + 2) % 3;
    if(t + 2 < 32) STG(bufS, t + 2);
    const short* As_b = &lds3[bufR][0];
    const short* Bs_b = &lds3[bufR][4096];
    short8 af[4], bfr[4];
    #pragma unroll
    for(int mi = 0; mi < 4; mi++){
      int ar = wm + mi * 16 + m16;
      af[mi] = *(const short8*)(As_b + ar * 32 + ((quad + (ar >> 1)) & 3) * 8);
    }
    #pragma unroll
    for(int ni = 0; ni < 4; ni++){
      int br = wn + ni * 16 + m16;
      bfr[ni] = *(const short8*)(Bs_b + br * 32 + ((quad + (br >> 1)) & 3) * 8);
    }
    __builtin_amdgcn_s_setprio(1);
    #pragma unroll
    for(int mi = 0; mi < 4; mi++)
      #pragma unroll
      for(int ni = 0; ni < 4; ni++)
        acc[mi][ni] = __builtin_amdgcn_mfma_f32_16x16x32_bf16(af[mi], bfr[ni], acc[mi][ni], 0, 0, 0);
    __builtin_amdgcn_s_setprio(0);
    __builtin_amdgcn_sched_barrier(0);
    if(t + 2 < 32){
      asm volatile("s_waitcnt vmcnt(4)" ::: "memory");
    } else if(t + 2 == 32){
      asm volatile("s_waitcnt vmcnt(0)" ::: "memory");
    }
    if(t < 31){
      __builtin_amdgcn_s_barrier();
      __builtin_amdgcn_sched_barrier(0);
    }
  }
  #pragma unroll
  for(int mi = 0; mi < 4; mi++){
    #pragma unroll
    for(int ni = 0; ni < 4; ni++){
      #pragma unroll
      for(int r = 0; r < 4; r++){
        int row = bm + wm + mi * 16 + quad * 4 + r;
        int col = bn + wn + ni * 16 + m16;
        float v = acc[mi][ni][r];
        if constexpr(EPI == GEPI_BF16){
          ((bf16*)Cv)[(size_t)row * 1024 + col] = f2b(v);
        } else if constexpr(EPI == GEPI_SILU){
          ((bf16*)Cv)[(size_t)row * 1024 + col] = f2b(v / (1.f + expf(-v)));
        } else { // GEPI_OUT
          size_t off = (size_t)(row + rowoff) * 1024 + col;
          if(oflag[0]) ((float*)Cv)[off] = v;
          else         ((bf16*)Cv)[off]  = f2b(v);
        }
      }
    }
  }
}

// ---------------------------------------------------------------- 256x128 proj4 GEMM, 8 waves, BK=32, 3-buf rotation
// grid (8, 32, 4), 512 threads. 2 blocks/CU (72 KB LDS) -> block-level TLP.
__global__ __launch_bounds__(512) void gemm256(Proj4 prm){
  __shared__ __align__(16) short lds3[3][12288];   // [buf][A:0..8191 | B:8192..12287]
  int tid = threadIdx.x;
  int flat = blockIdx.x + (blockIdx.y << 3) + (blockIdx.z << 8);
  int j = flat & 7, k = flat >> 3;
  int bn = (k & 7) << 7;
  int kk = k >> 3;
  int bm = ((j << 2) + (kk & 3)) << 8;
  int z  = kk >> 2;
  const bf16* __restrict__ A  = prm.A[z];
  const bf16* __restrict__ Bt = prm.Bt[z];
  bf16* __restrict__ C        = prm.C[z];
  int w = tid >> 6, lane = tid & 63;
  int wm = (w & 1) * 128, wn = (w >> 1) * 32;
  int m16 = lane & 15, quad = lane >> 4;

  f32x4 acc[8][2];
  #pragma unroll
  for(int mi = 0; mi < 8; mi++)
    #pragma unroll
    for(int ni = 0; ni < 2; ni++)
      acc[mi][ni] = (f32x4){0.f, 0.f, 0.f, 0.f};

  int srow = tid >> 2;                        // 0..127
  int c4   = ((tid & 3) - (srow >> 1)) & 3;   // rotated logical chunk to fetch
  const bf16* Ag = A  + (size_t)(bm + srow) * 1024 + c4 * 8;
  const bf16* Bg = Bt + (size_t)(bn + srow) * 1024 + c4 * 8;

  auto STG = [&](int buf, int t){
    int kb = t << 5;
    async16(Ag + kb,                          &lds3[buf][w * 512]);
    async16(Ag + (size_t)128 * 1024 + kb,     &lds3[buf][4096 + w * 512]);
    async16(Bg + kb,                          &lds3[buf][8192 + w * 512]);
  };
  STG(0, 0); STG(1, 1);
  asm volatile("s_waitcnt vmcnt(3)" ::: "memory");
  __builtin_amdgcn_s_barrier();
  __builtin_amdgcn_sched_barrier(0);

  #pragma unroll
  for(int t = 0; t < 32; t++){
    const int bufR = t % 3;
    const int bufS = (t + 2) % 3;
    if(t + 2 < 32) STG(bufS, t + 2);       // overlaps with this step's compute
    const short* As_b = &lds3[bufR][0];
    const short* Bs_b = &lds3[bufR][8192];
    short8 af[8], bfr[2];
    #pragma unroll
    for(int mi = 0; mi < 8; mi++){
      int ar = wm + mi * 16 + m16;
      af[mi] = *(const short8*)(As_b + ar * 32 + ((quad + (ar >> 1)) & 3) * 8);
    }
    #pragma unroll
    for(int ni = 0; ni < 2; ni++){
      int br = wn + ni * 16 + m16;
      bfr[ni] = *(const short8*)(Bs_b + br * 32 + ((quad + (br >> 1)) & 3) * 8);
    }
    __builtin_amdgcn_s_setprio(1);
    #pragma unroll
    for(int mi = 0; mi < 8; mi++)
      #pragma unroll
      for(int ni = 0; ni < 2; ni++)
        acc[mi][ni] = __builtin_amdgcn_mfma_f32_16x16x32_bf16(af[mi], bfr[ni], acc[mi][ni], 0, 0, 0);
    __builtin_amdgcn_s_setprio(0);
    __builtin_amdgcn_sched_barrier(0);
    if(t + 2 < 32){
      asm volatile("s_waitcnt vmcnt(3)" ::: "memory");   // tile t+1 landed
    } else if(t + 2 == 32){
      asm volatile("s_waitcnt vmcnt(0)" ::: "memory");   // tile 31 landed
    }
    if(t < 31){
      __builtin_amdgcn_s_barrier();          // single barrier per step
      __builtin_amdgcn_sched_barrier(0);
    }
  }
  bool silu = (z == 3);
  #pragma unroll
  for(int mi = 0; mi < 8; mi++){
    #pragma unroll
    for(int ni = 0; ni < 2; ni++){
      #pragma unroll
      for(int r = 0; r < 4; r++){
        int row = bm + wm + mi * 16 + quad * 4 + r;
        int col = bn + wn + ni * 16 + m16;
        float v = acc[mi][ni][r];
        if(silu) v = v / (1.f + expf(-v));
        C[(size_t)row * 1024 + col] = f2b(v);
      }
    }
  }
}

// ---------------------------------------------------------------- fused 5-channel mix (K=32 MFMA + mix epilogue), XCD-swizzled
__global__ __launch_bounds__(256) void gemm_mix(
    const bf16* __restrict__ xxx,   // [M][160] ld 256
    const bf16* __restrict__ w2T,   // [5][1024][32]
    const bf16* __restrict__ xg,
    MixP prm, int b0, int t0, int Llog2){
  const int Lm1 = (1 << Llog2) - 1;
  __shared__ __align__(16) short As[128 * 32];
  __shared__ __align__(16) short Bs[128 * 32];
  int tid = threadIdx.x;
  int bn, bm, c;
  xcd_swz_g(bn, bm, c);
  int w = tid >> 6, lane = tid & 63;
  int wm = (w & 1) * 64, wn = (w >> 1) * 64;
  int m16 = lane & 15, quad = lane >> 4;

  int srow = tid >> 2;
  int sk8  = (tid & 3) * 8;
  short* Al = As + w * 512;
  short* Bl = Bs + w * 512;
  #pragma unroll
  for(int rep = 0; rep < 2; rep++){
    async16(xxx + (size_t)(bm + srow + rep * 64) * 256 + c * 32 + sk8, Al + rep * 2048);
    async16(w2T + (size_t)c * 32768 + (size_t)(bn + srow + rep * 64) * 32 + sk8, Bl + rep * 2048);
  }
  __syncthreads();
  f32x4 acc[4][4];
  short8 af[4], bfr[4];
  #pragma unroll
  for(int mi = 0; mi < 4; mi++)
    af[mi] = *(const short8*)(As + (wm + mi * 16 + m16) * 32 + quad * 8);
  #pragma unroll
  for(int ni = 0; ni < 4; ni++)
    bfr[ni] = *(const short8*)(Bs + (wn + ni * 16 + m16) * 32 + quad * 8);
  #pragma unroll
  for(int mi = 0; mi < 4; mi++)
    #pragma unroll
    for(int ni = 0; ni < 4; ni++)
      acc[mi][ni] = __builtin_amdgcn_mfma_f32_16x16x32_bf16(
          af[mi], bfr[ni], (f32x4){0.f, 0.f, 0.f, 0.f}, 0, 0, 0);

  const bf16* maa = prm.maa[c];
  bf16* dst = prm.dst[c];
  #pragma unroll
  for(int mi = 0; mi < 4; mi++){
    #pragma unroll
    for(int ni = 0; ni < 4; ni++){
      #pragma unroll
      for(int r = 0; r < 4; r++){
        int row = bm + wm + mi * 16 + quad * 4 + r;
        int col = bn + wn + ni * 16 + m16;
        size_t grow = seg_grow(row, b0, t0, Llog2, Lm1);
        int tl = seg_t(row, t0, Lm1);
        float xc = b2f(xg[grow * Dd + col]);
        float xp = tl ? b2f(xg[(grow - 1) * Dd + col]) : 0.f;
        dst[(size_t)row * 1024 + col] =
            f2b(xc + (xp - xc) * (b2f(maa[col]) + acc[mi][ni][r]));
      }
    }
  }
}

// ---------------------------------------------------------------- generic MFMA GEMM (runtime N/K), XCD-swizzled
constexpr int G2_TANH = 0, G2_DECAY = 1;

template<int EPI>
__global__ __launch_bounds__(256) void gemm_mfma2(
    const bf16* __restrict__ A,
    const bf16* __restrict__ Bt,
    void* __restrict__ Cv, int ldc,
    int Ndim, int Kdim,
    const bf16* __restrict__ e_w){
  __shared__ __align__(16) short As[128 * 32];
  __shared__ __align__(16) short Bs[128 * 32];
  int tid = threadIdx.x;
  int bn, bm, zz;
  xcd_swz_g(bn, bm, zz);
  int w = tid >> 6, lane = tid & 63;
  int wm = (w & 1) * 64, wn = (w >> 1) * 64;
  int m16 = lane & 15, quad = lane >> 4;

  f32x4 acc[4][4];
  #pragma unroll
  for(int mi = 0; mi < 4; mi++)
    #pragma unroll
    for(int ni = 0; ni < 4; ni++)
      acc[mi][ni] = (f32x4){0.f, 0.f, 0.f, 0.f};

  int srow = tid >> 2;
  int sk8  = (tid & 3) * 8;
  const bf16* Ag = A  + (size_t)(bm + srow) * Kdim + sk8;
  const bf16* Bg = Bt + (size_t)(bn + srow) * Kdim + sk8;
  short* Al = As + w * 512;
  short* Bl = Bs + w * 512;

  for(int kb = 0; kb < Kdim; kb += 32){
    #pragma unroll
    for(int rep = 0; rep < 2; rep++){
      async16(Ag + (size_t)rep * 64 * Kdim + kb, Al + rep * 2048);
      async16(Bg + (size_t)rep * 64 * Kdim + kb, Bl + rep * 2048);
    }
    __syncthreads();
    short8 af[4], bfr[4];
    #pragma unroll
    for(int mi = 0; mi < 4; mi++)
      af[mi] = *(const short8*)(As + (wm + mi * 16 + m16) * 32 + quad * 8);
    #pragma unroll
    for(int ni = 0; ni < 4; ni++)
      bfr[ni] = *(const short8*)(Bs + (wn + ni * 16 + m16) * 32 + quad * 8);
    #pragma unroll
    for(int mi = 0; mi < 4; mi++)
      #pragma unroll
      for(int ni = 0; ni < 4; ni++)
        acc[mi][ni] = __builtin_amdgcn_mfma_f32_16x16x32_bf16(af[mi], bfr[ni], acc[mi][ni], 0, 0, 0);
    __syncthreads();
  }
  #pragma unroll
  for(int mi = 0; mi < 4; mi++){
    #pragma unroll
    for(int ni = 0; ni < 4; ni++){
      #pragma unroll
      for(int r = 0; r < 4; r++){
        int row = bm + wm + mi * 16 + quad * 4 + r;
        int col = bn + wn + ni * 16 + m16;
        if(col >= Ndim) continue;
        float v = acc[mi][ni][r];
        size_t off = (size_t)row * ldc + col;
        if constexpr(EPI == G2_TANH){
          ((bf16*)Cv)[off] = f2b(tanhf(v));
        } else { // G2_DECAY
          float td = b2f(e_w[col]) + v;
          ((float*)Cv)[off] = fmaxf(-expf(td), -5.2983173665480363f);
        }
      }
    }
  }
}

// ---------------------------------------------------------------- small VALU GEMM (segmented-out fallback only)
constexpr int EPI_OUTV = 5;
#define BM 64
#define BN 64
#define BK 16

template<int EPI>
__global__ __launch_bounds__(256) void gemm_ep(
    const bf16* __restrict__ A, int lda,
    const bf16* __restrict__ Bm, int ldb,
    void* __restrict__ Cv, int ldc,
    int Mdim, int Ndim, int Kdim,
    const bf16* __restrict__ xg, const bf16* __restrict__ e_w,
    int b0, int t0, int Llog2, const int* __restrict__ oflag){
  const int Lm1 = (1 << Llog2) - 1;
  __shared__ float As[BM][BK + 1];
  __shared__ float Bs[BK][BN + 4];
  int tid = threadIdx.x;
  int tx = tid & 15, ty = tid >> 4;
  int bm = blockIdx.y * BM, bn = blockIdx.x * BN;
  float acc[4][4] = {};
  for(int kb = 0; kb < Kdim; kb += BK){
    {
      int lr = tid >> 2;
      int lc = (tid & 3) * 4;
      int gr = bm + lr;
      #pragma unroll
      for(int q = 0; q < 4; q++){
        int gc = kb + lc + q;
        float av = 0.f;
        if(gr < Mdim && gc < Kdim)
          av = b2f(A[(size_t)gr * lda + gc]);
        As[lr][lc + q] = av;
      }
    }
    {
      int lr = tid >> 4;
      int lc = (tid & 15) * 4;
      #pragma unroll
      for(int q = 0; q < 4; q++){
        int gr = kb + lr; int gc = bn + lc + q;
        Bs[lr][lc + q] = (gr < Kdim && gc < Ndim) ? b2f(Bm[(size_t)gr * ldb + gc]) : 0.f;
      }
    }
    __syncthreads();
    #pragma unroll
    for(int kk = 0; kk < BK; kk++){
      float ar[4], br[4];
      #pragma unroll
      for(int q = 0; q < 4; q++) ar[q] = As[ty * 4 + q][kk];
      #pragma unroll
      for(int q = 0; q < 4; q++) br[q] = Bs[kk][tx * 4 + q];
      #pragma unroll
      for(int mi = 0; mi < 4; mi++)
        #pragma unroll
        for(int ni = 0; ni < 4; ni++)
          acc[mi][ni] += ar[mi] * br[ni];
    }
    __syncthreads();
  }
  #pragma unroll
  for(int mi = 0; mi < 4; mi++){
    int row = bm + ty * 4 + mi;
    if(row >= Mdim) continue;
    #pragma unroll
    for(int ni = 0; ni < 4; ni++){
      int col = bn + tx * 4 + ni;
      if(col >= Ndim) continue;
      float vacc = acc[mi][ni];
      size_t grow = seg_grow(row, b0, t0, Llog2, Lm1);
      size_t go = grow * Dd + col;
      if(oflag[0]) ((float*)Cv)[go] = vacc;
      else         ((bf16*)Cv)[go]  = f2b(vacc);
    }
  }
}

// ---------------------------------------------------------------- cumsum (in place wlog->wcum) + wse
// 8-wide load batching: loads are independent of the accumulator (only the
// stores depend), so batch 8 loads -> then 8 add+store. Cuts the exposed
// per-step memory latency ~8x at 1 wave/SIMD occupancy.
__global__ __launch_bounds__(256) void k_cumsum(float* __restrict__ wd,
                                                float* __restrict__ wse,
                                                int nlog2){
  int blk = blockIdx.x;
  int dg = blk & 3; int rest = blk >> 2;
  int nmask = (1 << nlog2) - 1;
  int ln = rest & nmask; int bp = rest >> nlog2;
  int d = dg * 256 + threadIdx.x;
  size_t rowbase = (((size_t)bp << nlog2) + ln) * 128;
  size_t base = rowbase * Dd + d;
  float c = 0.f;
  for(int t = 0; t < 128; t += 8){
    float v[8];
    #pragma unroll
    for(int q = 0; q < 8; q++)
      v[q] = wd[base + (size_t)(t + q) * Dd];
    #pragma unroll
    for(int q = 0; q < 8; q++){
      c += v[q];
      wd[base + (size_t)(t + q) * Dd] = c;
    }
  }
  int h = d >> 6, k0 = d & 63;
  wse[((((size_t)bp * Hh + h) << nlog2) | ln) * 64 + k0] = __expf(fminf(c, 0.f));
}

// ---------------------------------------------------------------- chunk1 (MFMA)
__global__ __launch_bounds__(256) void k_chunk1(const bf16* __restrict__ kb,
                                                const bf16* __restrict__ vb,
                                                const float* __restrict__ wcum,
                                                float* __restrict__ wkv,
                                                int nlog2){
  __shared__ __align__(16) bf16 ktT[64 * 136];
  __shared__ __align__(16) bf16 vT2[64 * 136];
  int tid = threadIdx.x, blk = blockIdx.x;
  int nmask = (1 << nlog2) - 1;
  int ln = blk & nmask; int rest = blk >> nlog2;
  int h = rest & 15; int bp = rest >> 4;
  size_t rowbase = (((size_t)bp << nlog2) + ln) * 128;
  size_t gbase = rowbase * Dd + h * 64;
  for(int r = 0; r < 32; r++){
    int idx = r * 256 + tid;
    int t0 = idx >> 6, k0 = idx & 63;
    size_t gi = gbase + (size_t)t0 * Dd + k0;
    float c  = wcum[gi];
    float cL = wcum[gbase + (size_t)127 * Dd + k0];
    ktT[k0 * 136 + t0] = f2b(b2f(kb[gi]) * __expf(fminf(cL - c, 0.f)));
    vT2[k0 * 136 + t0] = vb[gi];
  }
  __syncthreads();
  int w = tid >> 6, lane = tid & 63;
  int m16 = lane & 15, quad = lane >> 4;
  f32x4 acc[4];
  #pragma unroll
  for(int nt = 0; nt < 4; nt++) acc[nt] = (f32x4){0.f, 0.f, 0.f, 0.f};
  #pragma unroll
  for(int ks = 0; ks < 4; ks++){
    short8 af = *(const short8*)(ktT + (w * 16 + m16) * 136 + ks * 32 + quad * 8);
    #pragma unroll
    for(int nt = 0; nt < 4; nt++){
      short8 bfr = *(const short8*)(vT2 + (nt * 16 + m16) * 136 + ks * 32 + quad * 8);
      acc[nt] = __builtin_amdgcn_mfma_f32_16x16x32_bf16(af, bfr, acc[nt], 0, 0, 0);
    }
  }
  size_t obase = (size_t)blk * 4096;
  #pragma unroll
  for(int nt = 0; nt < 4; nt++)
    #pragma unroll
    for(int r = 0; r < 4; r++)
      wkv[obase + (size_t)(w * 16 + quad * 4 + r) * 64 + nt * 16 + m16] = acc[nt][r];
}

// ---------------------------------------------------------------- state scan, in place, carry in st
__global__ __launch_bounds__(256) void k_scan(float* __restrict__ buf,
                                              const float* __restrict__ wse,
                                              float* __restrict__ st,
                                              int b0, int firstseg, int nlog2){
  int blk = blockIdx.x;
  int h = blk & 15, bp = blk >> 4;
  int tid = threadIdx.x;
  size_t stbase = ((size_t)(b0 + bp) * Hh + h) * 4096;
  int nloc = 1 << nlog2;
  float s[16];
  #pragma unroll
  for(int r = 0; r < 16; r++)
    s[r] = firstseg ? 0.f : st[stbase + r * 256 + tid];
  for(int ln = 0; ln < nloc; ln++){
    size_t idx = (((size_t)bp * Hh + h) << nlog2) | ln;
    size_t base = idx * 4096;
    const float* wsp = wse + idx * 64;
    #pragma unroll
    for(int r = 0; r < 16; r++){
      int e = r * 256 + tid;
      float tmp = buf[base + e];
      buf[base + e] = s[r];
      s[r] = s[r] * wsp[e >> 6] + tmp;
    }
  }
  #pragma unroll
  for(int r = 0; r < 16; r++)
    st[stbase + r * 256 + tid] = s[r];
}

// ---------------------------------------------------------------- chunk2: full-MFMA intra attention + fused groupnorm(64)+gate
__global__ __launch_bounds__(256) void k_chunk2(
    const bf16* __restrict__ rb, const bf16* __restrict__ kb,
    const bf16* __restrict__ vb, const float* __restrict__ wcum,
    const float* __restrict__ states, const bf16* __restrict__ u,
    const bf16* __restrict__ gb, const bf16* __restrict__ lnw,
    const bf16* __restrict__ lnb, bf16* __restrict__ gated,
    int nlog2){
  __shared__ __align__(16) bf16 vT[64 * 136];
  __shared__ __align__(16) bf16 sT[64 * 72];
  __shared__ __align__(16) bf16 ascr[4 * 16 * 136];
  int tid = threadIdx.x, blk = blockIdx.x;
  int nmask = (1 << nlog2) - 1;
  int ln = blk & nmask; int rest = blk >> nlog2;
  int h = rest & 15; int bp = rest >> 4;
  size_t rowbase = (((size_t)bp << nlog2) + ln) * 128;
  size_t gbase = rowbase * Dd + h * 64;
  for(int r = 0; r < 32; r++){
    int idx = r * 256 + tid;
    int t0 = idx >> 6, v0 = idx & 63;
    vT[v0 * 136 + t0] = vb[gbase + (size_t)t0 * Dd + v0];
  }
  for(int r = 0; r < 16; r++){
    int idx = r * 256 + tid;
    int k0 = idx >> 6, v0 = idx & 63;
    sT[v0 * 72 + k0] = f2b(states[(size_t)blk * 4096 + k0 * 64 + v0]);
  }
  __syncthreads();
  int w = tid >> 6, lane = tid & 63;
  int m16 = lane & 15, quad = lane >> 4;
  bf16* scr = ascr + w * (16 * 136);
  f32x4 oacc[2][4];
  #pragma unroll
  for(int a1 = 0; a1 < 2; a1++)
    #pragma unroll
    for(int a2 = 0; a2 < 4; a2++) oacc[a1][a2] = (f32x4){0.f, 0.f, 0.f, 0.f};

  for(int ii = 0; ii < 2; ii++){
    int I = ii ? (7 - w) : w;
    int B = I * 16;
    for(int z = lane; z < 544; z += 64) ((unsigned long long*)scr)[z] = 0ULL;
    int i0 = B + m16;
    size_t rowi = rowbase + i0;
    short8 rf[2], af[2], rw2[2];
    float crv[2][8];
    #pragma unroll
    for(int ks = 0; ks < 2; ks++){
      int koff = h * 64 + ks * 32 + quad * 8;
      rf[ks] = *(const short8*)(rb + rowi * Dd + koff);
      float cp[8];
      if(i0 > 0){
        f32x4 c0 = *(const f32x4*)(wcum + (rowi - 1) * Dd + koff);
        f32x4 c1 = *(const f32x4*)(wcum + (rowi - 1) * Dd + koff + 4);
        #pragma unroll
        for(int c = 0; c < 4; c++){ cp[c] = c0[c]; cp[4 + c] = c1[c]; }
      } else {
        #pragma unroll
        for(int c = 0; c < 8; c++) cp[c] = 0.f;
      }
      if(B > 0){
        f32x4 c0 = *(const f32x4*)(wcum + (rowbase + B - 1) * Dd + koff);
        f32x4 c1 = *(const f32x4*)(wcum + (rowbase + B - 1) * Dd + koff + 4);
        #pragma unroll
        for(int c = 0; c < 4; c++){ crv[ks][c] = c0[c]; crv[ks][4 + c] = c1[c]; }
      } else {
        #pragma unroll
        for(int c = 0; c < 8; c++) crv[ks][c] = 0.f;
      }
      short8 av, wv;
      #pragma unroll
      for(int c = 0; c < 8; c++){
        float rv = b2f(((const bf16*)&rf[ks])[c]);
        ((bf16*)&av)[c] = f2b(rv * __expf(fminf(cp[c] - crv[ks][c], 0.f)));
        ((bf16*)&wv)[c] = f2b(rv * __expf(fminf(cp[c], 0.f)));
      }
      af[ks] = av; rw2[ks] = wv;
    }
    for(int J = 0; J < I; J++){
      f32x4 aacc = (f32x4){0.f, 0.f, 0.f, 0.f};
      #pragma unroll
      for(int ks = 0; ks < 2; ks++){
        int koff = h * 64 + ks * 32 + quad * 8;
        size_t rowj = rowbase + J * 16 + m16;
        short8 k8 = *(const short8*)(kb + rowj * Dd + koff);
        f32x4 c0 = *(const f32x4*)(wcum + rowj * Dd + koff);
        f32x4 c1 = *(const f32x4*)(wcum + rowj * Dd + koff + 4);
        short8 bfrag;
        #pragma unroll
        for(int c = 0; c < 8; c++){
          float kv = b2f(((const bf16*)&k8)[c]);
          float cj = (c < 4) ? c0[c] : c1[c - 4];
          ((bf16*)&bfrag)[c] = f2b(kv * __expf(fminf(crv[ks][c] - cj, 0.f)));
        }
        aacc = __builtin_amdgcn_mfma_f32_16x16x32_bf16(af[ks], bfrag, aacc, 0, 0, 0);
      }
      #pragma unroll
      for(int r = 0; r < 4; r++)
        scr[(quad * 4 + r) * 136 + J * 16 + m16] = f2b(aacc[r]);
    }
    {
      f32x4 aacc = (f32x4){0.f, 0.f, 0.f, 0.f};
      f32x4 dacc = (f32x4){0.f, 0.f, 0.f, 0.f};
      #pragma unroll
      for(int ks = 0; ks < 2; ks++){
        int koff = h * 64 + ks * 32 + quad * 8;
        size_t rowj = rowbase + B + m16;
        short8 k8 = *(const short8*)(kb + rowj * Dd + koff);
        f32x4 c0 = *(const f32x4*)(wcum + rowj * Dd + koff);
        f32x4 c1 = *(const f32x4*)(wcum + rowj * Dd + koff + 4);
        short8 u8 = *(const short8*)(u + h * 64 + ks * 32 + quad * 8);
        short8 bf1, bf2;
        #pragma unroll
        for(int c = 0; c < 8; c++){
          float kv = b2f(((const bf16*)&k8)[c]);
          float cj = (c < 4) ? c0[c] : c1[c - 4];
          ((bf16*)&bf1)[c] = f2b(kv * __expf(crv[ks][c] - cj));
          ((bf16*)&bf2)[c] = f2b(kv * b2f(((const bf16*)&u8)[c]));
        }
        aacc = __builtin_amdgcn_mfma_f32_16x16x32_bf16(af[ks], bf1, aacc, 0, 0, 0);
        dacc = __builtin_amdgcn_mfma_f32_16x16x32_bf16(rf[ks], bf2, dacc, 0, 0, 0);
      }
      #pragma unroll
      for(int r = 0; r < 4; r++){
        int row = quad * 4 + r, col = m16;
        if(col < row)       scr[row * 136 + B + col] = f2b(aacc[r]);
        else if(col == row) scr[row * 136 + B + col] = f2b(dacc[r]);
      }
    }
    asm volatile("s_waitcnt lgkmcnt(0)" ::: "memory");
    int nks = (I + 2) >> 1;
    for(int ks2 = 0; ks2 < nks; ks2++){
      short8 afr = *(const short8*)(scr + m16 * 136 + ks2 * 32 + quad * 8);
      #pragma unroll
      for(int nt = 0; nt < 4; nt++){
        short8 bfr = *(const short8*)(vT + (nt * 16 + m16) * 136 + ks2 * 32 + quad * 8);
        oacc[ii][nt] = __builtin_amdgcn_mfma_f32_16x16x32_bf16(afr, bfr, oacc[ii][nt], 0, 0, 0);
      }
    }
    #pragma unroll
    for(int ks = 0; ks < 2; ks++){
      #pragma unroll
      for(int nt = 0; nt < 4; nt++){
        short8 sfr = *(const short8*)(sT + (nt * 16 + m16) * 72 + ks * 32 + quad * 8);
        oacc[ii][nt] = __builtin_amdgcn_mfma_f32_16x16x32_bf16(rw2[ks], sfr, oacc[ii][nt], 0, 0, 0);
      }
    }
  }
  __syncthreads();
  // fused groupnorm(64) + gate: each wave holds rows B..B+15 x all 64 cols
  // of head h. Row (quad*4+r)'s 64 cols live in the 16 m16-lanes x 4 nt
  // fragments -> per-lane partial sums + shfl_xor over lane bits 0..3.
  #pragma unroll
  for(int ii = 0; ii < 2; ii++){
    int I = ii ? (7 - w) : w;
    int B = I * 16;
    #pragma unroll
    for(int r = 0; r < 4; r++){
      float s1 = 0.f, s2 = 0.f;
      #pragma unroll
      for(int nt = 0; nt < 4; nt++){
        float v = oacc[ii][nt][r];
        s1 += v; s2 += v * v;
      }
      #pragma unroll
      for(int off = 8; off > 0; off >>= 1){
        s1 += __shfl_xor(s1, off);
        s2 += __shfl_xor(s2, off);
      }
      float mu  = s1 * 0.015625f;
      float var = s2 * 0.015625f - mu * mu;
      float inv = rsqrtf(var + 6.4e-4f);
      int i0 = B + quad * 4 + r;
      size_t rowoff = gbase + (size_t)i0 * Dd;
      #pragma unroll
      for(int nt = 0; nt < 4; nt++){
        int v0 = nt * 16 + m16;
        float og = (oacc[ii][nt][r] - mu) * inv * b2f(lnw[h * 64 + v0]) + b2f(lnb[h * 64 + v0]);
        gated[rowoff + v0] = f2b(og * b2f(gb[rowoff + v0]));
      }
    }
  }
}

// ---------------------------------------------------------------- host
extern "C" void kernel_launch(void* const* d_in, const int* in_sizes, int n_in,
                              void* d_out, int out_size, void* d_ws, size_t ws_size,
                              hipStream_t stream){
  char* W = (char*)d_ws;
  size_t cur = 0;
  auto carve = [&](size_t bytes) -> char* {
    char* p = W + cur;
    cur = (cur + bytes + 255) & ~(size_t)255;
    return p;
  };

  int* flag = (int*)carve(4096);
  static const int NEL[20] = {8388608, 1024, 1024, 1024, 1024, 1024, 1024,
                              163840, 163840, 1024, 65536, 65536, 1024,
                              1048576, 1048576, 1048576, 1048576, 1048576,
                              1024, 1024};
  bf16* canon[20];
  for(int i = 0; i < 20; i++) canon[i] = (bf16*)carve((size_t)NEL[i] * 2);

  k_detect<<<dim3(1), 256, 0, stream>>>((const unsigned short*)d_in[0], flag);
  ConvP cp;
  for(int i = 0; i < 20; i++){ cp.src[i] = d_in[i]; cp.dst[i] = canon[i]; }
  k_conv_all<<<dim3(13770), 256, 0, stream>>>(cp, flag);

  const bf16* xp   = canon[0];
  const bf16* tmx  = canon[1];
  const bf16* tdec = canon[9];
  const bf16* up   = canon[12];
  const bf16* lnwp = canon[18];
  const bf16* lnbp = canon[19];

  bf16* WrT  = (bf16*)carve(2097152);
  bf16* WkT  = (bf16*)carve(2097152);
  bf16* WvT  = (bf16*)carve(2097152);
  bf16* WgT  = (bf16*)carve(2097152);
  bf16* WoT  = (bf16*)carve(2097152);
  bf16* W1T  = (bf16*)carve(256 * 1024 * 2);    // [256][1024], rows >=160 zero
  bf16* DW1T = (bf16*)carve(128 * 1024 * 2);    // [128][1024], rows >=64 zero
  bf16* DW2T = (bf16*)carve(1024 * 64 * 2);     // [1024][64]
  bf16* W2T  = (bf16*)carve(5 * 1024 * 32 * 2); // [5][1024][32]
  T5P tp;
  tp.src[0] = canon[13]; tp.dst[0] = WrT;
  tp.src[1] = canon[14]; tp.dst[1] = WkT;
  tp.src[2] = canon[15]; tp.dst[2] = WvT;
  tp.src[3] = canon[16]; tp.dst[3] = WgT;
  tp.src[4] = canon[17]; tp.dst[4] = WoT;
  k_transpose5<<<dim3(32, 32, 5), 256, 0, stream>>>(tp);
  k_transposeP<<<dim3(1024), 256, 0, stream>>>(canon[7],  W1T,  1024, 160, 256);
  k_transposeP<<<dim3(512),  256, 0, stream>>>(canon[10], DW1T, 1024, 64, 128);
  k_transposeP<<<dim3(256),  256, 0, stream>>>(canon[11], DW2T, 64, 1024, 1024);
  k_transposeP5<<<dim3(128, 1, 5), 256, 0, stream>>>(canon[8], W2T);

  float* st = (float*)carve(1u << 20);
  size_t FIXED = cur;

  // per-row bytes: xxx 512 + ww1 128 + wse 32 + xmx 2048 + mix 2048 + k/v/r/g 4*2048
  //              + wdec 4096 + wkvst 2048 = 19104
  const size_t UNIT = 19104, PAD = 65536;
  int nb, L;
  if(ws_size >= FIXED + (size_t)8192 * UNIT + PAD){ nb = 4; L = 2048; }
  else {
    nb = 1; L = 2048;
    while(L > 128 && ws_size < FIXED + (size_t)L * UNIT + PAD) L >>= 1;
  }
  const int Llog2 = __builtin_ctz((unsigned)L);
  const int nlog2 = Llog2 - 7;
  const int M     = nb * L;
  const size_t Mr = (size_t)M;

  bf16*  xxx    = (bf16*) carve(Mr * 512);     // [M][160] ld 256
  bf16*  ww1    = (bf16*) carve(Mr * 128);
  float* wse    = (float*)carve(Mr * 32);
  bf16*  xmx    = (bf16*) carve(Mr * 2048);
  bf16*  mixbuf = (bf16*) carve(Mr * 2048);
  bf16*  kbuf   = (bf16*) carve(Mr * 2048);
  bf16*  vbuf   = (bf16*) carve(Mr * 2048);
  bf16*  rbuf   = (bf16*) carve(Mr * 2048);
  bf16*  gbuf   = (bf16*) carve(Mr * 2048);
  float* wdec   = (float*)carve(Mr * 4096);
  float* wkvst  = (float*)carve(Mr * 2048);
  bf16*  gated  = mixbuf; // mixbuf dead after decay-tanh GEMM

  // channel overlay for the 5 fused-mix outputs (all dead-by-consumer ordering):
  //   mix5[0]=mixbuf (w, consumed by decay tanh), mix5[1]=wdec[0:16M] (k),
  //   mix5[2]=wdec[16M:32M] (v), mix5[3]=wkvst (r), mix5[4]=xmx (g, xmx dead post-LoRA)
  MixP mp;
  mp.maa[0] = canon[2]; mp.maa[1] = canon[3]; mp.maa[2] = canon[4];
  mp.maa[3] = canon[5]; mp.maa[4] = canon[6];
  mp.dst[0] = mixbuf;
  mp.dst[1] = (bf16*)wdec;
  mp.dst[2] = (bf16*)wdec + Mr * 1024;
  mp.dst[3] = (bf16*)wkvst;
  mp.dst[4] = xmx;

  Proj4 pp;
  pp.A[0] = mp.dst[1]; pp.Bt[0] = WkT; pp.C[0] = kbuf;
  pp.A[1] = mp.dst[2]; pp.Bt[1] = WvT; pp.C[1] = vbuf;
  pp.A[2] = mp.dst[3]; pp.Bt[2] = WrT; pp.C[2] = rbuf;
  pp.A[3] = mp.dst[4]; pp.Bt[3] = WgT; pp.C[3] = gbuf;

  for(int b0 = 0; b0 < 4; b0 += nb){
    for(int t0 = 0; t0 < Tt; t0 += L){
      // 1. xmx, then xxx = tanh(xmx @ w1)
      k_prep<<<dim3(M * 4), 256, 0, stream>>>(xp, tmx, xmx, b0, t0, Llog2);
      gemm_mfma2<G2_TANH><<<dim3(2, M/128), 256, 0, stream>>>(
          xmx, W1T, xxx, 256, 160, 1024, nullptr);
      // 2. fused 5-channel mix (xmx dead; overwritten as mix5[4])
      gemm_mix<<<dim3(8, M/128, 5), 256, 0, stream>>>(
          xxx, W2T, xp, mp, b0, t0, Llog2);
      // 3. four projections in one launch (256x128 tile, 3-buf pipeline, 2 blk/CU)
      if(M == 8192){
        gemm256<<<dim3(8, 32, 4), 512, 0, stream>>>(pp);
      } else {
        for(int z = 0; z < 4; z++){
          if(z == 3)
            gemm_mfma<GEPI_SILU><<<dim3(8, M/128), 256, 0, stream>>>(pp.A[z], pp.Bt[z], pp.C[z], flag, 0);
          else
            gemm_mfma<GEPI_BF16><<<dim3(8, M/128), 256, 0, stream>>>(pp.A[z], pp.Bt[z], pp.C[z], flag, 0);
        }
      }
      // 4. decay chain (consumes mix5[0]; writes wdec over mix5[1,2] — dead)
      gemm_mfma2<G2_TANH><<<dim3(1, M/128), 256, 0, stream>>>(
          mixbuf, DW1T, ww1, 64, 64, 1024, nullptr);
      gemm_mfma2<G2_DECAY><<<dim3(8, M/128), 256, 0, stream>>>(
          ww1, DW2T, wdec, 1024, 1024, 64, tdec);
      // 5. chunked WKV (chunk2 fuses groupnorm+gate -> gated directly)
      int nloc = 1 << nlog2;
      k_cumsum<<<dim3(nb * nloc * 4), 256, 0, stream>>>(wdec, wse, nlog2);
      k_chunk1<<<dim3(nb * 16 * nloc), 256, 0, stream>>>(kbuf, vbuf, wdec, wkvst, nlog2);
      k_scan<<<dim3(nb * 16), 256, 0, stream>>>(wkvst, wse, st, b0, (t0 == 0) ? 1 : 0, nlog2);
      k_chunk2<<<dim3(nb * 16 * nloc), 256, 0, stream>>>(
          rbuf, kbuf, vbuf, wdec, wkvst, up, gbuf, lnwp, lnbp, gated, nlog2);
      // 6. output projection (3-buf pipelined 128^2, 512 blocks)
      if(L == Tt){
        gemm_mfma<GEPI_OUT><<<dim3(8, M/128), 256, 0, stream>>>(gated, WoT, d_out, flag, b0 * Tt);
      } else {
        gemm_ep<EPI_OUTV><<<dim3(16, M/64), 256, 0, stream>>>(
            gated, 1024, canon[17], 1024, d_out, 1024, M, 1024, 1024,
            nullptr, nullptr, b0, t0, Llog2, flag);
      }
    }
  }
}